// Round 6
// baseline (247.888 us; speedup 1.0000x reference)
//
#include <hip/hip_runtime.h>
#include <hip/hip_bf16.h>
#include <cstdint>

// Problem constants
#define B_DIM 16384
#define DX 256
#define DH 512
#define DS 128
#define DT 128
#define KDIM 1024   // DX+DH+DS+DT
#define NDIM 2048   // 4*DH
#define HOUT 512

typedef __attribute__((ext_vector_type(8))) short short8;
typedef __attribute__((ext_vector_type(4))) float floatx4;

union bf16x8 {
  short8 v;
  __hip_bfloat16 b[8];
};

__device__ __forceinline__ float fast_sigmoid(float x) {
  return 1.f / (1.f + __expf(-x));
}
__device__ __forceinline__ float fast_tanh(float x) {
  float e = __expf(-2.f * x);
  return (1.f - e) / (1.f + e);
}

// ===========================================================================
// Tiled operand layouts (stage-ready chunk order):
//   A tile (mb,kb) = 128 rows x 64 k, 16 chunks of 512 bf16.
//   chunk t = s*8 + c  (s = 32-k panel, c = 16-row group)
//   chunk-lane i: row = c*16 + i/4, k = kb*64 + s*32 + (i&3)*8 (+j)
//   flat = ((mb*16 + kb)*16 + t)*512 + i*8 + j
// W identical over packed cols; packed col order
//   n_local = wn*64 + g*16 + hl  <->  hh = nblk*32 + wn*16 + hl,
//   original col = g*512 + hh    (g: 0=i,1=f,2=o,3=c~)
// ===========================================================================

#define PACKA_BLOCKS (B_DIM * KDIM / 8 / 256)   // 8192
#define PACKW_BLOCKS (NDIM * KDIM / 8 / 256)    // 1024

// Merged pack kernel: blocks [0,8192) do A, [8192,9216) do W.
__global__ __launch_bounds__(256) void pack_AW(
    const float* __restrict__ x, const float* __restrict__ h,
    const float* __restrict__ s, const float* __restrict__ t,
    const float* __restrict__ Wx, const float* __restrict__ Wh,
    const float* __restrict__ Ws, const float* __restrict__ Wt,
    __hip_bfloat16* __restrict__ Ap, __hip_bfloat16* __restrict__ Wp) {
  if (blockIdx.x < PACKA_BLOCKS) {
    int tid = blockIdx.x * 256 + threadIdx.x;  // 0 .. B_DIM*KDIM/8-1
    int i = tid & 63;
    int tt = (tid >> 6) & 15;
    int tile = tid >> 10;          // mb*16 + kb
    int kb = tile & 15, mb = tile >> 4;
    int sp = tt >> 3, c = tt & 7;
    int b = mb * 128 + c * 16 + (i >> 2);
    int k = kb * 64 + sp * 32 + (i & 3) * 8;
    const float* p;
    if (k < 256)      p = x + (size_t)b * DX + k;
    else if (k < 768) p = h + (size_t)b * DH + (k - 256);
    else if (k < 896) p = s + (size_t)b * DS + (k - 768);
    else              p = t + (size_t)b * DT + (k - 896);
    floatx4 v0 = *(const floatx4*)p;
    floatx4 v1 = *(const floatx4*)(p + 4);
    bf16x8 o;
#pragma unroll
    for (int j = 0; j < 4; ++j) {
      o.b[j]     = __float2bfloat16(v0[j]);
      o.b[4 + j] = __float2bfloat16(v1[j]);
    }
    *(short8*)(Ap + (size_t)tid * 8) = o.v;
  } else {
    int tid = (blockIdx.x - PACKA_BLOCKS) * 256 + threadIdx.x;
    int i = tid & 63;
    int tt = (tid >> 6) & 15;
    int tile = tid >> 10;          // nblk*16 + kb
    int kb = tile & 15, nblk = tile >> 4;
    int sp = tt >> 3, c = tt & 7;
    int nl = c * 16 + (i >> 2);    // local packed col 0..127
    int k = kb * 64 + sp * 32 + (i & 3) * 8;
    int wn = nl >> 6, g = (nl >> 4) & 3, hl = nl & 15;
    int col = g * 512 + nblk * 32 + wn * 16 + hl;
    const float* src; int kl;
    if (k < 256)      { src = Wx; kl = k; }
    else if (k < 768) { src = Wh; kl = k - 256; }
    else if (k < 896) { src = Ws; kl = k - 768; }
    else              { src = Wt; kl = k - 896; }
    bf16x8 o;
#pragma unroll
    for (int r = 0; r < 8; ++r)
      o.b[r] = __float2bfloat16(src[(size_t)(kl + r) * NDIM + col]);
    *(short8*)(Wp + (size_t)tid * 8) = o.v;
  }
}

// ---------------------------------------------------------------------------
// Fused GEMM + in-register LSTM epilogue, single-barrier double-buffered.
// 128x128 tile, 2x2 waves, 4x4 16x16x32 MFMA acc/wave, BK=32.
// Loads for panel p+1 are issued AFTER the barrier that starts panel p, so
// by the time the NEXT barrier's vmcnt(0) drain hits them, they've had a
// full compute phase in flight. LDS 32 KB (2x(8A+8B)).
// ---------------------------------------------------------------------------
__global__ __launch_bounds__(256, 4) void lstm_gemm(
    const __hip_bfloat16* __restrict__ Ap, const __hip_bfloat16* __restrict__ Wp,
    const float* __restrict__ bh, const float* __restrict__ c_in,
    float* __restrict__ out) {
  __shared__ unsigned short As[2][128 * 32];  // 2 x 8 KB
  __shared__ unsigned short Bs[2][128 * 32];  // 2 x 8 KB

  const int tid = threadIdx.x;
  const int lane = tid & 63;
  const int wid = tid >> 6;
  const int wm = wid & 1;        // row half (64 rows)
  const int wn = wid >> 1;       // col half (64 packed cols)
  const int q = lane >> 4;
  const int fr = lane & 15;
  const int mb = blockIdx.y;
  const int nblk = blockIdx.x;
  const int m0 = mb * 128;

  floatx4 acc[4][4];
#pragma unroll
  for (int i = 0; i < 4; ++i)
#pragma unroll
    for (int j = 0; j < 4; ++j) acc[i][j] = (floatx4)0.f;

  const int c0 = wid * 2;            // this wave's chunk pair
  const size_t lanoff = (size_t)lane * 8;

  // Issue staging loads for panel p into buffer (p&1).
  auto issue = [&](int p) {
    const size_t abase =
        ((size_t)((mb * 16 + (p >> 1)) * 16 + (p & 1) * 8)) * 512;
    const size_t bbase =
        ((size_t)((nblk * 16 + (p >> 1)) * 16 + (p & 1) * 8)) * 512;
    const int buf = p & 1;
#pragma unroll
    for (int j = 0; j < 2; ++j) {
      const int chunk = c0 + j;      // wave-uniform, 0..7
      __builtin_amdgcn_global_load_lds(
          (const __attribute__((address_space(1))) void*)
              (Ap + abase + (size_t)chunk * 512 + lanoff),
          (__attribute__((address_space(3))) void*)&As[buf][chunk * 512],
          16, 0, 0);
      __builtin_amdgcn_global_load_lds(
          (const __attribute__((address_space(1))) void*)
              (Wp + bbase + (size_t)chunk * 512 + lanoff),
          (__attribute__((address_space(3))) void*)&Bs[buf][chunk * 512],
          16, 0, 0);
    }
  };

  issue(0);
  for (int p = 0; p < 32; ++p) {
    __syncthreads();               // drains loads for panel p (in flight one
                                   // full compute phase), and fences reuse
    if (p + 1 < 32) issue(p + 1);  // prefetch into other buffer, post-barrier

    const int buf = p & 1;
    short8 af[4], bf[4];
#pragma unroll
    for (int i = 0; i < 4; ++i) {
      af[i] = *(const short8*)&As[buf][(wm * 64 + i * 16 + fr) * 32 + q * 8];
      bf[i] = *(const short8*)&Bs[buf][(wn * 64 + i * 16 + fr) * 32 + q * 8];
    }
#pragma unroll
    for (int mi = 0; mi < 4; ++mi)
#pragma unroll
      for (int ni = 0; ni < 4; ++ni)
        acc[mi][ni] = __builtin_amdgcn_mfma_f32_16x16x32_bf16(
            af[mi], bf[ni], acc[mi][ni], 0, 0, 0);
  }

  // ---- In-register epilogue ----
  // acc[mi][g]: rows wm*64+mi*16+q*4+r, gate g of hidden hh.
  const int hh = nblk * 32 + wn * 16 + fr;
  float bias[4];
#pragma unroll
  for (int g = 0; g < 4; ++g) bias[g] = bh[g * 512 + hh];

#pragma unroll
  for (int mi = 0; mi < 4; ++mi) {
#pragma unroll
    for (int r = 0; r < 4; ++r) {
      const size_t grow = (size_t)(m0 + wm * 64 + mi * 16 + q * 4 + r);
      const float pi = acc[mi][0][r] + bias[0];
      const float pf = acc[mi][1][r] + bias[1];
      const float po = acc[mi][2][r] + bias[2];
      const float pc = acc[mi][3][r] + bias[3];
      const float ig = fast_sigmoid(pi);
      const float fg = fast_sigmoid(pf);
      const float og = fast_sigmoid(po);
      const float cg = fast_tanh(pc);
      const float cc = fg * c_in[grow * HOUT + hh] + ig * cg;
      out[grow * HOUT + hh] = fast_tanh(og * cc);  // faithful: tanh(o*c_new)
      out[(size_t)B_DIM * HOUT + grow * HOUT + hh] = cc;
    }
  }
}

// ---------------------------------------------------------------------------
extern "C" void kernel_launch(void* const* d_in, const int* in_sizes, int n_in,
                              void* d_out, int out_size, void* d_ws, size_t ws_size,
                              hipStream_t stream) {
  const float* x  = (const float*)d_in[0];
  const float* h  = (const float*)d_in[1];
  const float* c  = (const float*)d_in[2];
  const float* sp = (const float*)d_in[3];
  const float* tp = (const float*)d_in[4];
  const float* Wx = (const float*)d_in[5];
  const float* Wh = (const float*)d_in[6];
  const float* bh = (const float*)d_in[7];
  const float* Ws = (const float*)d_in[8];
  const float* Wt = (const float*)d_in[9];
  float* out = (float*)d_out;

  __hip_bfloat16* Ap = (__hip_bfloat16*)d_ws;                                     // 32 MB
  __hip_bfloat16* Wp = (__hip_bfloat16*)((char*)d_ws + (size_t)B_DIM * KDIM * 2); // 4 MB

  pack_AW<<<dim3(PACKA_BLOCKS + PACKW_BLOCKS), dim3(256), 0, stream>>>(
      x, h, sp, tp, Wx, Wh, Ws, Wt, Ap, Wp);
  lstm_gemm<<<dim3(NDIM / 128, B_DIM / 128), dim3(256), 0, stream>>>(Ap, Wp, bh, c, out);
}